// Round 5
// baseline (675.759 us; speedup 1.0000x reference)
//
#include <hip/hip_runtime.h>
#include <hip/hip_fp16.h>

#define S_DIM 2048
#define B_DIM 32
#define E_DIM 1024
#define A_DIM 1024
#define D_DIM 1024
#define M_DIM (S_DIM * B_DIM)  // 65536

typedef _Float16 f16x8 __attribute__((ext_vector_type(8)));
typedef _Float16 f16x4 __attribute__((ext_vector_type(4)));
typedef float f32x4 __attribute__((ext_vector_type(4)));

#define OFF_ENC 0ull
#define OFF_WT  134217728ull
#define OFF_DP  (OFF_WT + 2097152ull)
#define OFF_EN  (OFF_DP + 131072ull)
#define OFF_WP  (OFF_EN + 262144ull)   // wc partials: 16*32*1024*4 = 2 MB

__device__ inline void load_lds16(const void* g, void* l) {
    __builtin_amdgcn_global_load_lds((const __attribute__((address_space(1))) void*)g,
                                     (__attribute__((address_space(3))) void*)l, 16, 0, 0);
}

// 2 float4 in, 1 f16x8 out per thread (16B stores).
__global__ void convert_enc_kernel(const float4* __restrict__ in, f16x8* __restrict__ out) {
    int idx = blockIdx.x * 256 + threadIdx.x;
    float4 f0 = in[idx * 2];
    float4 f1 = in[idx * 2 + 1];
    f16x8 o = { (_Float16)f0.x, (_Float16)f0.y, (_Float16)f0.z, (_Float16)f0.w,
                (_Float16)f1.x, (_Float16)f1.y, (_Float16)f1.z, (_Float16)f1.w };
    out[idx] = o;
}

__global__ void transpose_wenc_kernel(const float* __restrict__ W, _Float16* __restrict__ WT) {
    __shared__ _Float16 tile[32][33];
    int a0 = blockIdx.x * 32, e0 = blockIdx.y * 32;
    int tx = threadIdx.x & 31, ty = threadIdx.x >> 5;
    #pragma unroll
    for (int i = 0; i < 32; i += 8)
        tile[ty + i][tx] = (_Float16)W[(size_t)(e0 + ty + i) * A_DIM + a0 + tx];
    __syncthreads();
    #pragma unroll
    for (int i = 0; i < 32; i += 8)
        WT[(size_t)(a0 + ty + i) * E_DIM + e0 + tx] = tile[tx][ty + i];
}

// Atomic-free: grid (16 a-chunks, 4 b-groups). Thread owns (a, b0) and (a, b0+1)
// over the full D. Wd slice shared by the 4 b-groups (16 MB total reads).
__global__ void decproj_kernel(const float* __restrict__ dec, const float* __restrict__ Wd,
                               const float* __restrict__ bias, float* __restrict__ dp) {
    const int t = threadIdx.x;
    const int a = blockIdx.x * 64 + (t & 63);
    const int b0 = blockIdx.y * 8 + (t >> 6) * 2;
    float acc0 = 0.f, acc1 = 0.f;
    const float* d0 = dec + (size_t)b0 * D_DIM;
    const float* d1 = dec + (size_t)(b0 + 1) * D_DIM;
    #pragma unroll 8
    for (int d = 0; d < D_DIM; ++d) {
        float w = Wd[(size_t)d * A_DIM + a];
        acc0 += d0[d] * w;
        acc1 += d1[d] * w;
    }
    float bs = bias[a];
    dp[(size_t)b0 * A_DIM + a] = acc0 + bs;
    dp[(size_t)(b0 + 1) * A_DIM + a] = acc1 + bs;
}

// 256x256 tile, BK=32, 8 waves (2M x 4N, 128x64 per wave).
// 4-deep LDS tile ring (As[4]/Bs[4], 128 KiB), stage distance 3, fully
// unrolled -> compile-time slots. Register double-buffer of fragments across
// the tile boundary; ONE barrier per tile; counted vmcnt(4) per tile.
// Chunk-XOR swizzle (0-conflict, r3-verified). [UNCHANGED from r4]
__global__ __launch_bounds__(512, 2)
void energy_gemm_kernel(const _Float16* __restrict__ Af, const _Float16* __restrict__ Bt,
                        const float* __restrict__ dp, const float* __restrict__ v,
                        float* __restrict__ energy) {
    __shared__ alignas(16) _Float16 As[4][256 * 32];
    __shared__ alignas(16) _Float16 Bs[4][256 * 32];

    const int tid = threadIdx.x;
    const int wid = tid >> 6;
    const int lane = tid & 63;
    const int quad = lane >> 4;
    const int l15 = lane & 15;
    const int rsw = ((l15 >> 1) & 3);   // reader row-XOR term

    const int bid = blockIdx.x;
    const int xcd = bid & 7;
    const int local = bid >> 3;                 // 0..127
    const int m0 = (xcd * 32 + (local >> 2)) * 256;
    const int n0 = (local & 3) * 256;

    const int wm = (wid >> 2) * 128;            // 0 / 128
    const int wn = (wid & 3) * 64;              // 0..192

    const int lr = lane >> 2;
    const int lc = ((lane & 3) ^ ((lane >> 3) & 3)) * 8;
    const _Float16* Ag = Af + (size_t)(m0 + wid * 16 + lr) * E_DIM + lc;
    const _Float16* Bg = Bt + (size_t)(n0 + wid * 16 + lr) * E_DIM + lc;

#define STAGE_A(u)                                                              \
    {                                                                           \
        load_lds16(Ag + (size_t)(u) * 32, &As[(u) & 3][wid * 512]);             \
        load_lds16(Ag + (size_t)128 * E_DIM + (size_t)(u) * 32,                 \
                   &As[(u) & 3][(wid + 8) * 512]);                              \
    }
#define STAGE_B(u)                                                              \
    {                                                                           \
        load_lds16(Bg + (size_t)(u) * 32, &Bs[(u) & 3][wid * 512]);             \
        load_lds16(Bg + (size_t)128 * E_DIM + (size_t)(u) * 32,                 \
                   &Bs[(u) & 3][(wid + 8) * 512]);                              \
    }

    f32x4 acc[8][4] = {};
    f16x8 afA[8], bfA[4], afB[8], bfB[4];

    STAGE_A(0) STAGE_B(0)
    STAGE_A(1) STAGE_B(1)
    STAGE_A(2) STAGE_B(2)
    asm volatile("s_waitcnt vmcnt(4)" ::: "memory");
    __builtin_amdgcn_s_barrier();
    asm volatile("" ::: "memory");

    #pragma unroll
    for (int j = 0; j < 4; ++j)
        bfA[j] = *(const f16x8*)&Bs[0][(wn + j * 16 + l15) * 32 + (quad ^ rsw) * 8];
    #pragma unroll
    for (int i = 0; i < 8; ++i)
        afA[i] = *(const f16x8*)&As[0][(wm + i * 16 + l15) * 32 + (quad ^ rsw) * 8];

#define TILE(t, afC, bfC, afN, bfN)                                             \
    {                                                                           \
        if ((t) <= 28) { STAGE_A((t) + 3) STAGE_B((t) + 3) }                    \
        __builtin_amdgcn_s_setprio(1);                                          \
        _Pragma("unroll")                                                       \
        for (int i = 0; i < 8; ++i) {                                           \
            if ((t) < 31 && i < 4)                                              \
                bfN[i] = *(const f16x8*)&Bs[((t) + 1) & 3]                      \
                    [(wn + i * 16 + l15) * 32 + (quad ^ rsw) * 8];              \
            if ((t) < 31)                                                       \
                afN[i] = *(const f16x8*)&As[((t) + 1) & 3]                      \
                    [(wm + i * 16 + l15) * 32 + (quad ^ rsw) * 8];              \
            _Pragma("unroll")                                                   \
            for (int j = 0; j < 4; ++j)                                         \
                acc[i][j] = __builtin_amdgcn_mfma_f32_16x16x32_f16(             \
                    afC[i], bfC[j], acc[i][j], 0, 0, 0);                        \
        }                                                                       \
        __builtin_amdgcn_s_setprio(0);                                          \
        if ((t) <= 28)      asm volatile("s_waitcnt vmcnt(4)" ::: "memory");    \
        else if ((t) == 29) asm volatile("s_waitcnt vmcnt(0)" ::: "memory");    \
        if ((t) < 31) {                                                         \
            asm volatile("" ::: "memory");                                      \
            __builtin_amdgcn_s_barrier();                                       \
            asm volatile("" ::: "memory");                                      \
        }                                                                       \
    }

    #pragma unroll
    for (int tt = 0; tt < 32; tt += 2) {
        TILE(tt,     afA, bfA, afB, bfB)
        TILE(tt + 1, afB, bfB, afA, bfA)
    }
#undef TILE
#undef STAGE_A
#undef STAGE_B

    float vf[4];
    #pragma unroll
    for (int j = 0; j < 4; ++j) vf[j] = v[n0 + wn + j * 16 + l15];

    #pragma unroll
    for (int i = 0; i < 8; ++i) {
        #pragma unroll
        for (int r = 0; r < 4; ++r) {
            int m = m0 + wm + i * 16 + quad * 4 + r;   // m = s*32 + b
            int bidx = m & 31;
            float sum = 0.f;
            #pragma unroll
            for (int j = 0; j < 4; ++j) {
                int a = n0 + wn + j * 16 + l15;
                float x = acc[i][j][r] + dp[bidx * A_DIM + a];
                float ex = __expf(2.f * x);
                float th = 1.f - 2.f * __builtin_amdgcn_rcpf(ex + 1.f);
                sum += th * vf[j];
            }
            sum += __shfl_xor(sum, 1);
            sum += __shfl_xor(sum, 2);
            sum += __shfl_xor(sum, 4);
            sum += __shfl_xor(sum, 8);
            if (l15 == 0) atomicAdd(&energy[bidx * S_DIM + (m >> 5)], sum);
        }
    }
}

// one block per b column; energy [B][S] coalesced; noise [S][B] added here
__global__ void scan_alpha_kernel(const float* __restrict__ energy, const float* __restrict__ noise,
                                  float* __restrict__ alpha) {
    __shared__ float sc[256];
    __shared__ float red[256];
    const int b = blockIdx.x;
    const int t = threadIdx.x;
    float p[8], q[8];
    float prod = 1.f;
    #pragma unroll
    for (int k = 0; k < 8; ++k) {
        int s = t * 8 + k;
        float x = energy[b * S_DIM + s] + noise[s * B_DIM + b];
        p[k] = __builtin_amdgcn_rcpf(1.f + __expf(-x));
        q[k] = __builtin_amdgcn_rcpf(1.f + __expf(x));
        prod *= q[k];
    }
    sc[t] = prod;
    __syncthreads();
    for (int off = 1; off < 256; off <<= 1) {
        float mine = sc[t];
        float other = (t >= off) ? sc[t - off] : 1.f;
        __syncthreads();
        sc[t] = mine * other;
        __syncthreads();
    }
    float run = (t > 0) ? sc[t - 1] : 1.f;
    float lsum = 0.f;
    #pragma unroll
    for (int k = 0; k < 8; ++k) {
        int s = t * 8 + k;
        float al = p[k] * run;
        run *= q[k];
        if (s < S_DIM - 1) { alpha[s * B_DIM + b] = al; lsum += al; }
    }
    red[t] = lsum;
    __syncthreads();
    for (int off = 128; off > 0; off >>= 1) {
        if (t < off) red[t] += red[t + off];
        __syncthreads();
    }
    if (t == 0) {
        float tot = fminf(fmaxf(red[0], 0.f), 1.f);
        alpha[(S_DIM - 1) * B_DIM + b] = 1.f - tot;
    }
}

// grid (16 s-chunks, 32 b): same traversal as before, but writes per-chunk
// PARTIALS to workspace (plain stores) instead of 512K contended device
// atomicAdds. wcp layout [chunk(16)][b(32)][e(1024)] f32.
__global__ void wc_kernel(const _Float16* __restrict__ enc, const float* __restrict__ alpha,
                          float* __restrict__ wcp) {
    __shared__ float red[128][8];
    const int b = blockIdx.y;
    const int t = threadIdx.x;
    const int e0 = (t & 127) * 8;
    const int half = t >> 7;
    int s = blockIdx.x * 128 + half;
    float acc[8] = {};
    for (int i = 0; i < 64; ++i, s += 2) {
        float al = alpha[s * B_DIM + b];
        f16x8 r = *(const f16x8*)&enc[((size_t)s * B_DIM + b) * E_DIM + e0];
        #pragma unroll
        for (int k = 0; k < 8; ++k) acc[k] += al * (float)r[k];
    }
    if (half) {
        #pragma unroll
        for (int k = 0; k < 8; ++k) red[t - 128][k] = acc[k];
    }
    __syncthreads();
    if (!half) {
        float* out = wcp + ((size_t)blockIdx.x * B_DIM + b) * E_DIM + e0;
        #pragma unroll
        for (int k = 0; k < 8; ++k) out[k] = acc[k] + red[t][k];
    }
}

// wc[b][e] = sum over 16 chunks of wcp[c][b][e]. 2MB, L2-resident.
__global__ void wc_reduce_kernel(const float* __restrict__ wcp, float* __restrict__ wc) {
    int o = blockIdx.x * 256 + threadIdx.x;   // o = b*1024 + e, 0..32767
    float s = 0.f;
    #pragma unroll
    for (int c = 0; c < 16; ++c) s += wcp[(size_t)c * (B_DIM * E_DIM) + o];
    wc[o] = s;
}

extern "C" void kernel_launch(void* const* d_in, const int* in_sizes, int n_in,
                              void* d_out, int out_size, void* d_ws, size_t ws_size,
                              hipStream_t stream) {
    const float* dec   = (const float*)d_in[0];
    const float* enc   = (const float*)d_in[1];
    const float* noise = (const float*)d_in[2];
    const float* Wd    = (const float*)d_in[3];
    const float* We    = (const float*)d_in[4];
    const float* bias  = (const float*)d_in[5];
    const float* v     = (const float*)d_in[6];

    char* ws = (char*)d_ws;
    _Float16* encf = (_Float16*)(ws + OFF_ENC);
    _Float16* wtf  = (_Float16*)(ws + OFF_WT);
    float* dp      = (float*)(ws + OFF_DP);
    float* energy  = (float*)(ws + OFF_EN);
    float* wcp     = (float*)(ws + OFF_WP);

    float* wc    = (float*)d_out;
    float* alpha = (float*)d_out + B_DIM * E_DIM;

    (void)hipMemsetAsync(energy, 0, M_DIM * sizeof(float), stream);

    convert_enc_kernel<<<dim3(M_DIM * E_DIM / 8 / 256), 256, 0, stream>>>((const float4*)enc, (f16x8*)encf);
    transpose_wenc_kernel<<<dim3(32, 32), 256, 0, stream>>>(We, wtf);
    decproj_kernel<<<dim3(16, 4), 256, 0, stream>>>(dec, Wd, bias, dp);
    energy_gemm_kernel<<<dim3(1024), 512, 0, stream>>>(encf, wtf, dp, v, energy);
    scan_alpha_kernel<<<dim3(32), 256, 0, stream>>>(energy, noise, alpha);
    wc_kernel<<<dim3(16, 32), 256, 0, stream>>>(encf, alpha, wcp);
    wc_reduce_kernel<<<dim3(128), 256, 0, stream>>>(wcp, wc);
}